// Round 22
// baseline (90.387 us; speedup 1.0000x reference)
//
#include <hip/hip_runtime.h>
#include <math.h>

#define RSTR  272                  // u8 tile row stride: 17 x 16B groups
#define TILEB (32 * RSTR)          // 8704 B per tile (32 rows)
#define PSTR  136                  // partial stride per spatial lane: 4q*32B + 8 pad

// v_sad_u8: d = c + sum_k |a.byte[k] - b.byte[k]|
__device__ __forceinline__ unsigned sad8(unsigned a, unsigned b, unsigned c) {
    unsigned d;
    asm("v_sad_u8 %0, %1, %2, %3" : "=v"(d) : "v"(a), "v"(b), "v"(c));
    return d;
}

// quantize one 256-f32 row -> 64 packed u8 dwords + f32-exact row sum
__device__ __forceinline__ void quant_row(const float* __restrict__ src,
                                          unsigned* __restrict__ dst,
                                          float* __restrict__ rsp, int lane) {
    float4 g = *(const float4*)(src + 4 * lane);
    const float k = 255.0f;
    unsigned q0 = (unsigned)(k / (1.0f + __expf(-g.x)) + 0.5f);
    unsigned q1 = (unsigned)(k / (1.0f + __expf(-g.y)) + 0.5f);
    unsigned q2 = (unsigned)(k / (1.0f + __expf(-g.z)) + 0.5f);
    unsigned q3 = (unsigned)(k / (1.0f + __expf(-g.w)) + 0.5f);
    dst[lane] = q0 | (q1 << 8) | (q2 << 16) | (q3 << 24);
    int sum = (int)(q0 + q1 + q2 + q3);
    #pragma unroll
    for (int s = 32; s >= 1; s >>= 1)
        sum += __shfl_xor(sum, s, 64);
    if (lane == 0) *rsp = (float)sum;              // <= 65280: f32-exact
}

// ---- fused: row-0/col-0 blocks produce quantized groups; all blocks consume
// ---- via device-scope flag spin; main body identical to R15/R21. ----
__global__ __launch_bounds__(256, 4)
void jaccard_fused(const float* __restrict__ x1, const float* __restrict__ x2,
                   unsigned* __restrict__ Aq, unsigned* __restrict__ Bq,
                   float* __restrict__ rs, int* __restrict__ flags,
                   float* __restrict__ out) {
    __shared__ char ATile[TILEB];
    __shared__ char BTile[TILEB];
    __shared__ char Part[64 * PSTR];   // [s 64][q 4][m 4] uint2

    const int bi = blockIdx.x, bj = blockIdx.y;    // 32 x 32 tiles
    const int tid = threadIdx.x, lane = tid & 63, wid = tid >> 6;

    // ---- production: block (bi,0) -> A-group bi; block (0,bj) -> B-group bj ----
    if (bj == 0) {
        for (int rr = wid; rr < 32; rr += 4) {
            const int row = bi * 32 + rr;
            quant_row(x1 + (size_t)row * 256, Aq + (size_t)row * 64, &rs[row], lane);
        }
        __syncthreads();
        if (tid == 0)
            __hip_atomic_store(&flags[bi], 1, __ATOMIC_RELEASE, __HIP_MEMORY_SCOPE_AGENT);
    }
    if (bi == 0) {
        for (int rr = wid; rr < 32; rr += 4) {
            const int row = bj * 32 + rr;
            quant_row(x2 + (size_t)row * 256, Bq + (size_t)row * 64, &rs[1024 + row], lane);
        }
        __syncthreads();
        if (tid == 0)
            __hip_atomic_store(&flags[32 + bj], 1, __ATOMIC_RELEASE, __HIP_MEMORY_SCOPE_AGENT);
    }

    // ---- acquire: wait for A-group bi and B-group bj ----
    if (tid == 0) {
        while (!__hip_atomic_load(&flags[bi], __ATOMIC_ACQUIRE, __HIP_MEMORY_SCOPE_AGENT))
            __builtin_amdgcn_s_sleep(8);
        while (!__hip_atomic_load(&flags[32 + bj], __ATOMIC_ACQUIRE, __HIP_MEMORY_SCOPE_AGENT))
            __builtin_amdgcn_s_sleep(8);
    }
    __syncthreads();

    // ---- R15 main body (byte-identical) ----
    const uint4* AqU4 = (const uint4*)Aq;
    const uint4* BqU4 = (const uint4*)Bq;

    #pragma unroll
    for (int k = 0; k < 2; ++k) {
        const int flat = tid + 256 * k;            // 0..511
        const int row = flat >> 4, c16 = flat & 15;
        uint4 va = AqU4[(size_t)(bi * 32 + row) * 16 + c16];
        *(uint4*)(ATile + row * RSTR + c16 * 16) = va;
        uint4 vb = BqU4[(size_t)(bj * 32 + row) * 16 + c16];
        *(uint4*)(BTile + row * RSTR + c16 * 16) = vb;
    }
    __syncthreads();

    const int s  = tid & 63;
    const int q  = tid >> 6;        // D-quarter, wave-uniform
    const int tx = s & 7;           // cols {tx + 8n}
    const int ty = s >> 3;          // rows {ty + 8m}

    const char* ab = ATile + ty * RSTR + q * 64;
    const char* bb = BTile + tx * RSTR + q * 64;

    unsigned acc[4][4] = {};
    #pragma unroll
    for (int cc = 0; cc < 4; ++cc) {               // 4 x 16B chunks per quarter
        uint4 av[4], bv[4];
        #pragma unroll
        for (int m = 0; m < 4; ++m)
            av[m] = *(const uint4*)(ab + m * (8 * RSTR) + cc * 16);   // 8-addr broadcast
        #pragma unroll
        for (int n = 0; n < 4; ++n)
            bv[n] = *(const uint4*)(bb + n * (8 * RSTR) + cc * 16);   // 8-addr broadcast
        #pragma unroll
        for (int m = 0; m < 4; ++m)
            #pragma unroll
            for (int n = 0; n < 4; ++n) {
                unsigned a = acc[m][n];
                a = sad8(av[m].x, bv[n].x, a);
                a = sad8(av[m].y, bv[n].y, a);
                a = sad8(av[m].z, bv[n].z, a);
                a = sad8(av[m].w, bv[n].w, a);
                acc[m][n] = a;
            }
    }

    {
        char* pw = Part + s * PSTR + q * 32;
        #pragma unroll
        for (int m = 0; m < 4; ++m) {
            unsigned p0 = acc[m][0] | (acc[m][1] << 16);   // each <= 16320
            unsigned p1 = acc[m][2] | (acc[m][3] << 16);
            *(uint2*)(pw + m * 8) = make_uint2(p0, p1);
        }
    }
    __syncthreads();

    const int s2 = tid & 63;
    const int m2 = tid >> 6;
    const int tx2 = s2 & 7;
    const int ty2 = s2 >> 3;

    unsigned sd0 = 0, sd1 = 0, sd2 = 0, sd3 = 0;
    const char* pr = Part + s2 * PSTR + m2 * 8;
    #pragma unroll
    for (int qq = 0; qq < 4; ++qq) {
        uint2 p = *(const uint2*)(pr + qq * 32);
        sd0 += p.x & 0xffff; sd1 += p.x >> 16;
        sd2 += p.y & 0xffff; sd3 += p.y >> 16;
    }

    const int i  = bi * 32 + ty2 + 8 * m2;
    const int j0 = bj * 32 + tx2;

    const float sa  = rs[i];
    const float sb0 = rs[1024 + j0];
    const float sb1 = rs[1024 + j0 + 8];
    const float sb2 = rs[1024 + j0 + 16];
    const float sb3 = rs[1024 + j0 + 24];

    const float t0 = sa + sb0, t1 = sa + sb1, t2 = sa + sb2, t3 = sa + sb3;
    const float i0 = 0.5f * (t0 - (float)sd0);
    const float i1 = 0.5f * (t1 - (float)sd1);
    const float i2 = 0.5f * (t2 - (float)sd2);
    const float i3 = 0.5f * (t3 - (float)sd3);
    const float v0 = i0 / (t0 - i0);
    const float v1 = i1 / (t1 - i1);
    const float v2 = i2 / (t2 - i2);
    const float v3 = i3 / (t3 - i3);

    float* outT = out + (size_t)1024 * 1024;
    out[(size_t)i * 1024 + j0]      = v0;
    out[(size_t)i * 1024 + j0 + 8]  = v1;
    out[(size_t)i * 1024 + j0 + 16] = v2;
    out[(size_t)i * 1024 + j0 + 24] = v3;
    outT[(size_t)j0        * 1024 + i] = v0;
    outT[(size_t)(j0 + 8)  * 1024 + i] = v1;
    outT[(size_t)(j0 + 16) * 1024 + i] = v2;
    outT[(size_t)(j0 + 24) * 1024 + i] = v3;
}

extern "C" void kernel_launch(void* const* d_in, const int* in_sizes, int n_in,
                              void* d_out, int out_size, void* d_ws, size_t ws_size,
                              hipStream_t stream) {
    const float* x1 = (const float*)d_in[0];
    const float* x2 = (const float*)d_in[1];
    float* out = (float*)d_out;

    unsigned* Aq    = (unsigned*)d_ws;                  // 256 KB
    unsigned* Bq    = Aq + (size_t)1024 * 64;           // 256 KB
    float*    rs    = (float*)(Bq + (size_t)1024 * 64); // 8 KB
    int*      flags = (int*)(rs + 2048);                // 64 ints

    // flags must be zero every call (ws is poisoned once, not re-poisoned)
    hipMemsetAsync(flags, 0, 64 * sizeof(int), stream);

    jaccard_fused<<<dim3(32, 32), 256, 0, stream>>>(x1, x2, Aq, Bq, rs, flags, out);
}

// Round 23
// 15.926 us; speedup vs baseline: 5.6753x; 5.6753x over previous
//
#include <hip/hip_runtime.h>
#include <math.h>

#define RSTR  272                  // u8 tile row stride: 17 x 16B groups
#define TILEB (32 * RSTR)          // 8704 B per tile (32 rows)
#define PSTR  136                  // partial stride per spatial lane: 4q*32B + 8 pad

// v_sad_u8: d = c + sum_k |a.byte[k] - b.byte[k]|
__device__ __forceinline__ unsigned sad8(unsigned a, unsigned b, unsigned c) {
    unsigned d;
    asm("v_sad_u8 %0, %1, %2, %3" : "=v"(d) : "v"(a), "v"(b), "v"(c));
    return d;
}

// ---- prepass: sigmoid -> u8 (x255, round) + integer row sums (f32-exact) ----
__global__ __launch_bounds__(256)
void prepass(const float* __restrict__ x1, const float* __restrict__ x2,
             unsigned* __restrict__ Aq, unsigned* __restrict__ Bq,
             float* __restrict__ rs) {
    const int wid = threadIdx.x >> 6, lane = threadIdx.x & 63;
    const int r = blockIdx.x * 4 + wid;            // 0..2047
    const bool isA = (r < 1024);
    const int row = isA ? r : (r - 1024);
    const float* src = (isA ? x1 : x2) + (size_t)row * 256;

    float4 g = *(const float4*)(src + 4 * lane);
    const float k = 255.0f;
    unsigned q0 = (unsigned)(k / (1.0f + __expf(-g.x)) + 0.5f);
    unsigned q1 = (unsigned)(k / (1.0f + __expf(-g.y)) + 0.5f);
    unsigned q2 = (unsigned)(k / (1.0f + __expf(-g.z)) + 0.5f);
    unsigned q3 = (unsigned)(k / (1.0f + __expf(-g.w)) + 0.5f);

    (isA ? Aq : Bq)[(size_t)row * 64 + lane] = q0 | (q1 << 8) | (q2 << 16) | (q3 << 24);

    int sum = (int)(q0 + q1 + q2 + q3);
    #pragma unroll
    for (int s = 32; s >= 1; s >>= 1)
        sum += __shfl_xor(sum, s, 64);
    if (lane == 0) rs[r] = (float)sum;             // <= 65280: f32-exact
}

// ---- main: 32x32 tiles, 256-thread blocks, 4 blocks/CU for phase overlap ----
__global__ __launch_bounds__(256, 4)
void jaccard_main(const uint4* __restrict__ Aq, const uint4* __restrict__ Bq,
                  const float* __restrict__ rs, float* __restrict__ out) {
    __shared__ char ATile[TILEB];
    __shared__ char BTile[TILEB];
    __shared__ char Part[64 * PSTR];   // [s 64][q 4][m 4] uint2

    const int bi = blockIdx.x, bj = blockIdx.y;    // 32 x 32 tiles
    const int tid = threadIdx.x;

    // ---- staging: 2 uint4 loads + 2 b128 LDS writes per thread per tile ----
    #pragma unroll
    for (int k = 0; k < 2; ++k) {
        const int flat = tid + 256 * k;            // 0..511
        const int row = flat >> 4, c16 = flat & 15;
        uint4 va = Aq[(size_t)(bi * 32 + row) * 16 + c16];
        *(uint4*)(ATile + row * RSTR + c16 * 16) = va;
        uint4 vb = Bq[(size_t)(bj * 32 + row) * 16 + c16];
        *(uint4*)(BTile + row * RSTR + c16 * 16) = vb;
    }
    __syncthreads();

    // wave = one D-quarter q (bytes [64q,64q+64)); spatial 8x8, microtile 4x4
    const int s  = tid & 63;
    const int q  = tid >> 6;        // 0..3, wave-uniform
    const int tx = s & 7;           // cols {tx + 8n}
    const int ty = s >> 3;          // rows {ty + 8m}

    const char* ab = ATile + ty * RSTR + q * 64;
    const char* bb = BTile + tx * RSTR + q * 64;

    unsigned acc[4][4] = {};
    #pragma unroll
    for (int cc = 0; cc < 4; ++cc) {               // 4 x 16B chunks per quarter
        uint4 av[4], bv[4];
        #pragma unroll
        for (int m = 0; m < 4; ++m)
            av[m] = *(const uint4*)(ab + m * (8 * RSTR) + cc * 16);   // 8-addr broadcast
        #pragma unroll
        for (int n = 0; n < 4; ++n)
            bv[n] = *(const uint4*)(bb + n * (8 * RSTR) + cc * 16);   // 8-addr broadcast
        #pragma unroll
        for (int m = 0; m < 4; ++m)
            #pragma unroll
            for (int n = 0; n < 4; ++n) {
                unsigned a = acc[m][n];
                a = sad8(av[m].x, bv[n].x, a);
                a = sad8(av[m].y, bv[n].y, a);
                a = sad8(av[m].z, bv[n].z, a);
                a = sad8(av[m].w, bv[n].w, a);
                acc[m][n] = a;
            }
    }

    // ---- partials: u16-packed [s][q][m], b64 each; 136B stride -> 2-way banks ----
    {
        char* pw = Part + s * PSTR + q * 32;
        #pragma unroll
        for (int m = 0; m < 4; ++m) {
            unsigned p0 = acc[m][0] | (acc[m][1] << 16);   // each <= 16320
            unsigned p1 = acc[m][2] | (acc[m][3] << 16);
            *(uint2*)(pw + m * 8) = make_uint2(p0, p1);
        }
    }
    __syncthreads();

    // ---- reduce + epilogue: thread (s2, m2) owns row ty2+8*m2, cols {tx2+8n} ----
    const int s2 = tid & 63;
    const int m2 = tid >> 6;
    const int tx2 = s2 & 7;
    const int ty2 = s2 >> 3;

    unsigned sd0 = 0, sd1 = 0, sd2 = 0, sd3 = 0;
    const char* pr = Part + s2 * PSTR + m2 * 8;
    #pragma unroll
    for (int qq = 0; qq < 4; ++qq) {
        uint2 p = *(const uint2*)(pr + qq * 32);
        sd0 += p.x & 0xffff; sd1 += p.x >> 16;
        sd2 += p.y & 0xffff; sd3 += p.y >> 16;
    }

    const int i  = bi * 32 + ty2 + 8 * m2;
    const int j0 = bj * 32 + tx2;

    const float sa  = rs[i];
    const float sb0 = rs[1024 + j0];
    const float sb1 = rs[1024 + j0 + 8];
    const float sb2 = rs[1024 + j0 + 16];
    const float sb3 = rs[1024 + j0 + 24];

    const float t0 = sa + sb0, t1 = sa + sb1, t2 = sa + sb2, t3 = sa + sb3;
    const float i0 = 0.5f * (t0 - (float)sd0);
    const float i1 = 0.5f * (t1 - (float)sd1);
    const float i2 = 0.5f * (t2 - (float)sd2);
    const float i3 = 0.5f * (t3 - (float)sd3);
    const float v0 = i0 / (t0 - i0);
    const float v1 = i1 / (t1 - i1);
    const float v2 = i2 / (t2 - i2);
    const float v3 = i3 / (t3 - i3);

    float* outT = out + (size_t)1024 * 1024;
    out[(size_t)i * 1024 + j0]      = v0;
    out[(size_t)i * 1024 + j0 + 8]  = v1;
    out[(size_t)i * 1024 + j0 + 16] = v2;
    out[(size_t)i * 1024 + j0 + 24] = v3;
    outT[(size_t)j0        * 1024 + i] = v0;
    outT[(size_t)(j0 + 8)  * 1024 + i] = v1;
    outT[(size_t)(j0 + 16) * 1024 + i] = v2;
    outT[(size_t)(j0 + 24) * 1024 + i] = v3;
}

extern "C" void kernel_launch(void* const* d_in, const int* in_sizes, int n_in,
                              void* d_out, int out_size, void* d_ws, size_t ws_size,
                              hipStream_t stream) {
    const float* x1 = (const float*)d_in[0];
    const float* x2 = (const float*)d_in[1];
    float* out = (float*)d_out;

    unsigned* Aq = (unsigned*)d_ws;                 // 256 KB
    unsigned* Bq = Aq + (size_t)1024 * 64;          // 256 KB
    float*    rs = (float*)(Bq + (size_t)1024 * 64);// 8 KB

    prepass<<<512, 256, 0, stream>>>(x1, x2, Aq, Bq, rs);
    jaccard_main<<<dim3(32, 32), 256, 0, stream>>>((const uint4*)Aq, (const uint4*)Bq,
                                                   rs, out);
}